// Round 8
// baseline (48.321 us; speedup 1.0000x reference)
//
#include <hip/hip_runtime.h>

// Batched Gram-Schmidt with PINNED cross-batch prefetch:
// each 192-thread block processes 2 batches; batch-1 loads are issued before
// batch-0 compute and pinned with sched_barrier(0) so the compiler cannot
// sink them (R6/R7 failure mode: VGPR=52/60 proved the prefetch was deleted).
// Batch-1's memory latency drains under batch-0's ~2us compute span.
// R4 phase structure: batched per-phase dots, pipelined shuffle reduces,
// one LDS cross-wave combine + barrier per phase, fused multi-axpy,
// normalization deferred into nontemporal stores.

#define S_VECS 8
#define CHUNKS 192  // float4 chunks per vector (768/4)

typedef float f32x4 __attribute__((ext_vector_type(4)));

__device__ __forceinline__ float wave_reduce_sum(float x) {
#pragma unroll
    for (int off = 32; off >= 1; off >>= 1)
        x += __shfl_xor(x, off, 64);
    return x;
}

__device__ __forceinline__ void load_batch(float (&v)[S_VECS][4],
                                           const float* __restrict__ in,
                                           size_t b, int chunk) {
    const f32x4* src = reinterpret_cast<const f32x4*>(in) + b * (S_VECS * CHUNKS);
#pragma unroll
    for (int s = 0; s < S_VECS; ++s) {
        f32x4 f = src[s * CHUNKS + chunk];
        v[s][0] = f.x; v[s][1] = f.y; v[s][2] = f.z; v[s][3] = f.w;
    }
}

__device__ __forceinline__ void process_store(float (&v)[S_VECS][4],
                                              float (*red)[S_VECS][3],
                                              int wave, int lane, int w1, int w2,
                                              float* __restrict__ out,
                                              size_t b, int chunk) {
    float inv_n[S_VECS];

#pragma unroll
    for (int i = 1; i < S_VECS; ++i) {
        const int p = i & 1;
        float d[S_VECS];
#pragma unroll
        for (int j = 0; j < S_VECS; ++j) {
            if (j < i) {
                float acc = 0.f;
#pragma unroll
                for (int e = 0; e < 4; ++e) acc += v[i][e] * v[j][e];
                d[j] = acc;
            }
        }
        float self = 0.f;
#pragma unroll
        for (int e = 0; e < 4; ++e) self += v[i - 1][e] * v[i - 1][e];

#pragma unroll
        for (int j = 0; j < S_VECS; ++j) {
            if (j < i) d[j] = wave_reduce_sum(d[j]);
        }
        self = wave_reduce_sum(self);

        if (lane == 0) {
#pragma unroll
            for (int j = 0; j < S_VECS; ++j) {
                if (j < i) red[p][j][wave] = d[j];
            }
            red[p][i][wave] = self;
        }
        __syncthreads();
#pragma unroll
        for (int j = 0; j < S_VECS; ++j) {
            if (j < i) d[j] += red[p][j][w1] + red[p][j][w2];
        }
        self += red[p][i][w1] + red[p][i][w2];
        inv_n[i - 1] = 1.0f / self;

#pragma unroll
        for (int j = 0; j < S_VECS; ++j) {
            if (j < i) {
                const float proj = d[j] * inv_n[j];
#pragma unroll
                for (int e = 0; e < 4; ++e) v[i][e] -= proj * v[j][e];
            }
        }
    }
    {
        float self = 0.f;
#pragma unroll
        for (int e = 0; e < 4; ++e) self += v[S_VECS - 1][e] * v[S_VECS - 1][e];
        self = wave_reduce_sum(self);
        if (lane == 0) red[0][0][wave] = self;
        __syncthreads();
        self += red[0][0][w1] + red[0][0][w2];
        inv_n[S_VECS - 1] = 1.0f / self;
    }

    f32x4* dst = reinterpret_cast<f32x4*>(out) + b * (S_VECS * CHUNKS);
#pragma unroll
    for (int s = 0; s < S_VECS; ++s) {
        const float inv_norm = sqrtf(inv_n[s]);
        f32x4 f;
        f.x = v[s][0] * inv_norm;
        f.y = v[s][1] * inv_norm;
        f.z = v[s][2] * inv_norm;
        f.w = v[s][3] * inv_norm;
        __builtin_nontemporal_store(f, &dst[s * CHUNKS + chunk]);
    }
}

__global__ __launch_bounds__(192)
void gram_schmidt_kernel(const float* __restrict__ in, float* __restrict__ out) {
    const int wave = threadIdx.x >> 6;   // 0..2
    const int lane = threadIdx.x & 63;
    const int chunk = wave * 64 + lane;  // 0..191

    __shared__ float red[2][S_VECS][3];  // [parity][value][wave]
    const int w1 = (wave == 2) ? 0 : wave + 1;
    const int w2 = (wave == 0) ? 2 : wave - 1;

    const size_t bA = (size_t)blockIdx.x * 2;
    const size_t bB = bA + 1;

    float vA[S_VECS][4], vB[S_VECS][4];

    // batch A loads
    load_batch(vA, in, bA, chunk);
    // PREFETCH batch B now; pin issue position — nothing may cross.
    load_batch(vB, in, bB, chunk);
    __builtin_amdgcn_sched_barrier(0);

    // batch A compute+store runs while B's loads are in flight
    process_store(vA, red, wave, lane, w1, w2, out, bA, chunk);

    __builtin_amdgcn_sched_barrier(0);
    process_store(vB, red, wave, lane, w1, w2, out, bB, chunk);
}

extern "C" void kernel_launch(void* const* d_in, const int* in_sizes, int n_in,
                              void* d_out, int out_size, void* d_ws, size_t ws_size,
                              hipStream_t stream) {
    const float* in = (const float*)d_in[0];
    float* out = (float*)d_out;
    const int B = in_sizes[0] / (S_VECS * 768);  // 4096
    gram_schmidt_kernel<<<B / 2, 192, 0, stream>>>(in, out);
}

// Round 10
// 42.437 us; speedup vs baseline: 1.1387x; 1.1387x over previous
//
#include <hip/hip_runtime.h>

// REVERT to R4 — best measured passing kernel (42.56 us harness).
// Batched Gram-Schmidt: 3 waves (192 threads) per batch.
// Each lane owns exactly ONE float4 of each of the 8 vectors -> 32 floats of
// live state (no spill, VGPR=36). Dots: per-lane 4-elem partial -> 6-step
// shuffle wave reduce -> cross-wave combine via 96B LDS (double-buffered by
// phase parity, one barrier per phase). Batched CGS-style dots + fused
// multi-axpy (==MGS to ~1e-8: finalized residuals are fp32-orthogonal).
// Normalization deferred to the store. Builtin nontemporal stores (safe,
// coherent — unlike ISA-level nt sc1 write-around, which left stale zero
// lines in non-local XCD L2s and failed validation in R9).

#define S_VECS 8
#define D_DIM 768
#define CHUNKS 192  // float4 chunks per vector

typedef float f32x4 __attribute__((ext_vector_type(4)));

__device__ __forceinline__ float wave_reduce_sum(float x) {
#pragma unroll
    for (int off = 32; off >= 1; off >>= 1)
        x += __shfl_xor(x, off, 64);
    return x;
}

__global__ __launch_bounds__(192)
void gram_schmidt_kernel(const float* __restrict__ in, float* __restrict__ out) {
    const int wave = threadIdx.x >> 6;   // 0..2
    const int lane = threadIdx.x & 63;
    const int b = blockIdx.x;
    const int chunk = wave * 64 + lane;  // 0..191

    __shared__ float red[2][S_VECS][3];  // [parity][value][wave]

    const int w1 = (wave == 2) ? 0 : wave + 1;
    const int w2 = (wave == 0) ? 2 : wave - 1;

    // ---- load: one float4 per vector per lane, fully coalesced ----
    float v[S_VECS][4];
    const f32x4* src = reinterpret_cast<const f32x4*>(in) + (size_t)b * (S_VECS * CHUNKS);
#pragma unroll
    for (int s = 0; s < S_VECS; ++s) {
        f32x4 f = src[s * CHUNKS + chunk];
        v[s][0] = f.x; v[s][1] = f.y; v[s][2] = f.z; v[s][3] = f.w;
    }

    float inv_n[S_VECS];  // 1 / <u_j, u_j> of finalized (unnormalized) residuals

#pragma unroll
    for (int i = 1; i < S_VECS; ++i) {
        const int p = i & 1;
        // --- batched per-lane partial dots d[j] = <v_i, u_j>, plus fused
        //     self-dot of the residual finalized last iteration ---
        float d[S_VECS];
#pragma unroll
        for (int j = 0; j < S_VECS; ++j) {
            if (j < i) {
                float acc = 0.f;
#pragma unroll
                for (int e = 0; e < 4; ++e) acc += v[i][e] * v[j][e];
                d[j] = acc;
            }
        }
        float self = 0.f;
#pragma unroll
        for (int e = 0; e < 4; ++e) self += v[i - 1][e] * v[i - 1][e];

        // --- wave-level reductions (independent chains, pipelined) ---
#pragma unroll
        for (int j = 0; j < S_VECS; ++j) {
            if (j < i) d[j] = wave_reduce_sum(d[j]);
        }
        self = wave_reduce_sum(self);

        // --- cross-wave combine: lane0 writes, barrier, broadcast reads ---
        if (lane == 0) {
#pragma unroll
            for (int j = 0; j < S_VECS; ++j) {
                if (j < i) red[p][j][wave] = d[j];
            }
            red[p][i][wave] = self;
        }
        __syncthreads();
#pragma unroll
        for (int j = 0; j < S_VECS; ++j) {
            if (j < i) d[j] += red[p][j][w1] + red[p][j][w2];
        }
        self += red[p][i][w1] + red[p][i][w2];
        inv_n[i - 1] = 1.0f / self;

        // --- fused multi-axpy: v_i -= sum_j (d_j / n_j) * u_j ---
#pragma unroll
        for (int j = 0; j < S_VECS; ++j) {
            if (j < i) {
                const float proj = d[j] * inv_n[j];
#pragma unroll
                for (int e = 0; e < 4; ++e) v[i][e] -= proj * v[j][e];
            }
        }
    }

    // ---- self-dot of the last residual ----
    {
        float self = 0.f;
#pragma unroll
        for (int e = 0; e < 4; ++e) self += v[S_VECS - 1][e] * v[S_VECS - 1][e];
        self = wave_reduce_sum(self);
        if (lane == 0) red[0][0][wave] = self;
        __syncthreads();
        self += red[0][0][w1] + red[0][0][w2];
        inv_n[S_VECS - 1] = 1.0f / self;
    }

    // ---- store with deferred normalization, builtin nontemporal ----
    f32x4* dst = reinterpret_cast<f32x4*>(out) + (size_t)b * (S_VECS * CHUNKS);
#pragma unroll
    for (int s = 0; s < S_VECS; ++s) {
        const float inv_norm = sqrtf(inv_n[s]);  // 1/sqrt(n)
        f32x4 f;
        f.x = v[s][0] * inv_norm;
        f.y = v[s][1] * inv_norm;
        f.z = v[s][2] * inv_norm;
        f.w = v[s][3] * inv_norm;
        __builtin_nontemporal_store(f, &dst[s * CHUNKS + chunk]);
    }
}

extern "C" void kernel_launch(void* const* d_in, const int* in_sizes, int n_in,
                              void* d_out, int out_size, void* d_ws, size_t ws_size,
                              hipStream_t stream) {
    const float* in = (const float*)d_in[0];
    float* out = (float*)d_out;
    const int B = in_sizes[0] / (S_VECS * D_DIM);  // 4096
    gram_schmidt_kernel<<<B, 192, 0, stream>>>(in, out);
}